// Round 1
// baseline (286.229 us; speedup 1.0000x reference)
//
#include <hip/hip_runtime.h>
#include <cmath>

#define Bb 32
#define Ss 2048
#define Hh 768
#define Oo 768
#define Kk 64

// Kernel A: per-batch attention. grid = B blocks x 256 threads.
//  - zero the (B,S) attention-weight output slab for this batch
//  - scores over the 64 gathered rows (wave-per-row dot products)
//  - dedup'd softmax (token_idxs sorted -> duplicate == previous)
//  - scatter aw, compute pooled[b] into workspace
__global__ __launch_bounds__(256) void attn_pool_kernel(
    const float* __restrict__ hidden,
    const int*   __restrict__ idxs,
    const float* __restrict__ subj,
    const float* __restrict__ Wa,
    const float* __restrict__ ba,
    float* __restrict__ aw_out,
    float* __restrict__ pooled)
{
    const int b    = blockIdx.x;
    const int tid  = threadIdx.x;
    const int lane = tid & 63;
    const int wave = tid >> 6;

    __shared__ int   s_idx[Kk];
    __shared__ float s_aw[Kk];     // scores, then attention weights
    __shared__ float s_red[4];
    __shared__ float s_const;

    // 1) zero aw output row (poisoned 0xAA by harness)
    float4* awz = (float4*)(aw_out + (size_t)b * Ss);
    for (int i = tid; i < Ss / 4; i += 256) awz[i] = make_float4(0.f, 0.f, 0.f, 0.f);

    if (tid < Kk) s_idx[tid] = idxs[b * Kk + tid];
    __syncthreads();

    // 2) sconst = subj[b] . Wa[0:H] + ba
    {
        float p = 0.f;
        for (int h = tid; h < Hh; h += 256)
            p += subj[b * Hh + h] * Wa[h];
        #pragma unroll
        for (int m = 32; m >= 1; m >>= 1) p += __shfl_xor(p, m);
        if (lane == 0) s_red[wave] = p;
        __syncthreads();
        if (tid == 0) s_const = s_red[0] + s_red[1] + s_red[2] + s_red[3] + ba[0];
        __syncthreads();
    }

    // 3) scores: wave w handles rows j = w, w+4, ...
    for (int j = wave; j < Kk; j += 4) {
        const float* row = hidden + ((size_t)b * Ss + s_idx[j]) * Hh;
        float p = 0.f;
        #pragma unroll
        for (int t = 0; t < Hh / 64; ++t)
            p += row[lane + 64 * t] * Wa[Hh + lane + 64 * t];
        #pragma unroll
        for (int m = 32; m >= 1; m >>= 1) p += __shfl_xor(p, m);
        if (lane == 0) s_aw[j] = p + s_const;
    }
    __syncthreads();

    // 4) softmax over unique positions (wave 0; 64 lanes = 64 slots)
    if (wave == 0) {
        const int j = lane;
        const bool active = (j == 0) || (s_idx[j] != s_idx[j - 1]);
        float sc = active ? s_aw[j] : -3.0e38f;
        float mx = sc;
        #pragma unroll
        for (int m = 32; m >= 1; m >>= 1) mx = fmaxf(mx, __shfl_xor(mx, m));
        float e = active ? expf(sc - mx) : 0.f;
        float sum = e;
        #pragma unroll
        for (int m = 32; m >= 1; m >>= 1) sum += __shfl_xor(sum, m);
        const float aw = e / sum;          // 0 for duplicate slots
        s_aw[j] = aw;
        if (active) aw_out[(size_t)b * Ss + s_idx[j]] = aw;
    }
    __syncthreads();

    // 5) pooled[b,h] = sum_j aw_j * hidden[b, idx_j, h]  (dupes have aw=0)
    for (int h = tid; h < Hh; h += 256) {
        float acc = 0.f;
        #pragma unroll 8
        for (int j = 0; j < Kk; ++j)
            acc += s_aw[j] * hidden[((size_t)b * Ss + s_idx[j]) * Hh + h];
        pooled[b * Hh + h] = acc;
    }
}

// Kernel B: out[b,o] = tanh(pooled[b] . Wo[:,o] + bo[o])
// grid = B * (O/64) blocks x 64 threads; one o-column per thread.
__global__ __launch_bounds__(64) void gemm_tanh_kernel(
    const float* __restrict__ pooled,
    const float* __restrict__ Wo,
    const float* __restrict__ bo,
    float* __restrict__ out)
{
    const int b     = blockIdx.x / (Oo / 64);
    const int chunk = blockIdx.x % (Oo / 64);
    const int o     = chunk * 64 + threadIdx.x;

    __shared__ float p[Hh];
    float4* p4 = (float4*)p;
    const float4* src = (const float4*)(pooled + b * Hh);
    for (int i = threadIdx.x; i < Hh / 4; i += 64) p4[i] = src[i];
    __syncthreads();

    float a0 = 0.f, a1 = 0.f, a2 = 0.f, a3 = 0.f;
    #pragma unroll 4
    for (int h = 0; h < Hh; h += 4) {
        const float4 pv = *(const float4*)&p[h];   // wave-uniform LDS broadcast
        a0 = fmaf(pv.x, Wo[(h + 0) * Oo + o], a0);
        a1 = fmaf(pv.y, Wo[(h + 1) * Oo + o], a1);
        a2 = fmaf(pv.z, Wo[(h + 2) * Oo + o], a2);
        a3 = fmaf(pv.w, Wo[(h + 3) * Oo + o], a3);
    }
    out[b * Oo + o] = tanhf(a0 + a1 + a2 + a3 + bo[o]);
}

extern "C" void kernel_launch(void* const* d_in, const int* in_sizes, int n_in,
                              void* d_out, int out_size, void* d_ws, size_t ws_size,
                              hipStream_t stream) {
    const float* hidden = (const float*)d_in[0];
    const int*   idxs   = (const int*)d_in[1];
    const float* subj   = (const float*)d_in[2];
    const float* Wa     = (const float*)d_in[3];
    const float* ba     = (const float*)d_in[4];
    const float* Wo     = (const float*)d_in[5];
    const float* bo     = (const float*)d_in[6];

    float* out    = (float*)d_out;            // transformed: B*O floats
    float* aw_out = out + Bb * Oo;            // attention_weights: B*S floats
    float* pooled = (float*)d_ws;             // B*H floats scratch

    attn_pool_kernel<<<Bb, 256, 0, stream>>>(hidden, idxs, subj, Wa, ba, aw_out, pooled);
    gemm_tanh_kernel<<<Bb * (Oo / 64), 64, 0, stream>>>(pooled, Wo, bo, out);
}

// Round 2
// 262.581 us; speedup vs baseline: 1.0901x; 1.0901x over previous
//
#include <hip/hip_runtime.h>
#include <cmath>

#define Bb 32
#define Ss 2048
#define Hh 768
#define Oo 768
#define Kk 64

// K1: one wave per (b,j) score; also zero the aw_out slab.
// grid 512 x 256 (2048 waves).
__global__ __launch_bounds__(256) void scores_kernel(
    const float* __restrict__ hidden,
    const int*   __restrict__ idxs,
    const float* __restrict__ Wa,
    float* __restrict__ scores,   // ws[0:2048]
    float* __restrict__ aw_out)
{
    const int tid  = threadIdx.x;
    const int lane = tid & 63;
    const int wid  = blockIdx.x * 4 + (tid >> 6);   // 0..2047
    const int gid  = blockIdx.x * 256 + tid;

    // zero attention-weight output (B*S = 65536 floats = 16384 float4)
    if (gid < (Bb * Ss / 4))
        ((float4*)aw_out)[gid] = make_float4(0.f, 0.f, 0.f, 0.f);

    const int b = wid >> 6;
    const int j = wid & 63;
    const int t_idx = idxs[b * Kk + j];

    const float4* row4 = (const float4*)(hidden + ((size_t)b * Ss + t_idx) * Hh);
    const float4* wa4  = (const float4*)(Wa + Hh);
    float p = 0.f;
    #pragma unroll
    for (int t = 0; t < 3; ++t) {
        const float4 r = row4[lane + 64 * t];
        const float4 w = wa4[lane + 64 * t];
        p += r.x * w.x + r.y * w.y + r.z * w.z + r.w * w.w;
    }
    #pragma unroll
    for (int m = 32; m >= 1; m >>= 1) p += __shfl_xor(p, m);
    if (lane == 0) scores[wid] = p;
}

// K2: per-batch softmax with dedupe + scatter. grid 32 x 64.
__global__ __launch_bounds__(64) void softmax_kernel(
    const int*   __restrict__ idxs,
    const float* __restrict__ subj,
    const float* __restrict__ Wa,
    const float* __restrict__ ba,
    const float* __restrict__ scores,
    float* __restrict__ aw,       // ws[2048:4096]
    float* __restrict__ aw_out)
{
    const int b = blockIdx.x;
    const int j = threadIdx.x;   // 0..63

    // sconst = subj[b] . Wa[0:H] + ba  (butterfly leaves sum in all lanes)
    const float4* s4  = (const float4*)(subj + b * Hh);
    const float4* wa4 = (const float4*)Wa;
    float p = 0.f;
    #pragma unroll
    for (int t = 0; t < 3; ++t) {
        const float4 r = s4[j + 64 * t];
        const float4 w = wa4[j + 64 * t];
        p += r.x * w.x + r.y * w.y + r.z * w.z + r.w * w.w;
    }
    #pragma unroll
    for (int m = 32; m >= 1; m >>= 1) p += __shfl_xor(p, m);
    const float sconst = p + ba[0];

    const int  myidx   = idxs[b * Kk + j];
    const int  previdx = (j > 0) ? idxs[b * Kk + j - 1] : -1;
    const bool active  = (j == 0) || (myidx != previdx);

    float sc = active ? (scores[b * Kk + j] + sconst) : -3.0e38f;
    float mx = sc;
    #pragma unroll
    for (int m = 32; m >= 1; m >>= 1) mx = fmaxf(mx, __shfl_xor(mx, m));
    const float e = active ? expf(sc - mx) : 0.f;
    float sum = e;
    #pragma unroll
    for (int m = 32; m >= 1; m >>= 1) sum += __shfl_xor(sum, m);
    const float w = e / sum;       // duplicates get 0

    aw[b * Kk + j] = w;
    if (active) aw_out[(size_t)b * Ss + myidx] = w;
}

// K3: per (b, o-chunk of 256): pooled into LDS, then h-split-4 GEMM + tanh.
// grid 96 x 1024 (16 waves/block).
__global__ __launch_bounds__(1024) void pool_gemm_kernel(
    const float* __restrict__ hidden,
    const int*   __restrict__ idxs,
    const float* __restrict__ aw,
    const float* __restrict__ Wo,
    const float* __restrict__ bo,
    float* __restrict__ out)
{
    const int b   = blockIdx.x / 3;
    const int oc  = blockIdx.x % 3;
    const int tid = threadIdx.x;

    __shared__ float s_aw[Kk];
    __shared__ int   s_idx[Kk];
    __shared__ float s_pool[Hh];
    __shared__ float s_part[4 * 256];

    if (tid < Kk) {
        s_aw[tid]  = aw[b * Kk + tid];
        s_idx[tid] = idxs[b * Kk + tid];
    }
    __syncthreads();

    // pooled[b, tid] (threads 768..1023 idle here)
    if (tid < Hh) {
        float acc = 0.f;
        #pragma unroll 8
        for (int j = 0; j < Kk; ++j)
            acc += s_aw[j] * hidden[((size_t)b * Ss + s_idx[j]) * Hh + tid];
        s_pool[tid] = acc;
    }
    __syncthreads();

    // GEMM: o = oc*256 + (tid&255), h-group = tid>>8 covers 192 h's
    const int ol = tid & 255;
    const int o  = oc * 256 + ol;
    const int hg = tid >> 8;
    const int h0 = hg * 192;
    float acc = 0.f;
    #pragma unroll 8
    for (int h = h0; h < h0 + 192; ++h)
        acc = fmaf(s_pool[h], Wo[h * Oo + o], acc);
    s_part[hg * 256 + ol] = acc;
    __syncthreads();

    if (tid < 256) {
        const int oo = oc * 256 + tid;
        const float s = s_part[tid] + s_part[256 + tid] + s_part[512 + tid]
                      + s_part[768 + tid] + bo[oo];
        out[b * Oo + oo] = tanhf(s);
    }
}

extern "C" void kernel_launch(void* const* d_in, const int* in_sizes, int n_in,
                              void* d_out, int out_size, void* d_ws, size_t ws_size,
                              hipStream_t stream) {
    const float* hidden = (const float*)d_in[0];
    const int*   idxs   = (const int*)d_in[1];
    const float* subj   = (const float*)d_in[2];
    const float* Wa     = (const float*)d_in[3];
    const float* ba     = (const float*)d_in[4];
    const float* Wo     = (const float*)d_in[5];
    const float* bo     = (const float*)d_in[6];

    float* out    = (float*)d_out;            // transformed: B*O floats
    float* aw_out = out + Bb * Oo;            // attention_weights: B*S floats
    float* scores = (float*)d_ws;             // [B*K]
    float* aw     = scores + Bb * Kk;         // [B*K]

    scores_kernel <<<512, 256, 0, stream>>>(hidden, idxs, Wa, scores, aw_out);
    softmax_kernel<<<Bb, 64, 0, stream>>>(idxs, subj, Wa, ba, scores, aw, aw_out);
    pool_gemm_kernel<<<Bb * 3, 1024, 0, stream>>>(hidden, idxs, aw, Wo, bo, out);
}